// Round 1
// 2066.668 us; speedup vs baseline: 1.3692x; 1.3692x over previous
//
#include <hip/hip_runtime.h>
#include <hip/hip_bf16.h>
#include <math.h>

typedef __hip_bfloat16 bf16;
typedef unsigned int u32;

__device__ __forceinline__ float b2f(bf16 x){ return __bfloat162float(x); }
__device__ __forceinline__ bf16  f2b(float x){ return __float2bfloat16(x); }
__device__ __forceinline__ float lo16(u32 u){ return __uint_as_float(u << 16); }
__device__ __forceinline__ float hi16(u32 u){ return __uint_as_float(u & 0xFFFF0000u); }
// float -> bf16 bits with round-to-nearest-even
__device__ __forceinline__ u32 bfbits(float x){
    u32 u = __float_as_uint(x);
    return (u + 0x7FFFu + ((u >> 16) & 1u)) >> 16;
}

#define RSQRT8 0.35355339059327373f

// inputs are PROVEN f32 (R1/R2 bf16 interpretation -> NaN; R3/R4 probe-selected f32 -> pass)

// ---------------- seg starts (idx_ji sorted) ----------------
__global__ void seg_start_kernel(const int* __restrict__ idx_ji, int T,
                                 int* __restrict__ seg, int E)
{
    int e = blockIdx.x * blockDim.x + threadIdx.x;
    if (e > E) return;
    int lo = 0, hi = T;
    while (lo < hi) { int mid = (lo + hi) >> 1; if (idx_ji[mid] < e) lo = mid + 1; else hi = mid; }
    seg[e] = lo;
}

__global__ void marker_kernel(float* out, int n){
    int i = blockIdx.x * blockDim.x + threadIdx.x;
    if (i < n) out[i] = 12345.0f;
}

// ---------------- q = MLP_hq(h_bond) per edge -> bf16 ----------------
__global__ __launch_bounds__(128) void q_kernel(
    const float* __restrict__ W1, const float* __restrict__ B1,
    const float* __restrict__ G,  const float* __restrict__ Bln,
    const float* __restrict__ W2, const float* __restrict__ B2,
    const float* __restrict__ h_bond, bf16* __restrict__ qout, int E)
{
    __shared__ u32 sW[128*65];       // [dim][row-pair] packed bf16, row stride 130 bf16
    __shared__ float sH[16][130];
    __shared__ float sX[128];
    __shared__ float sRed[4];
    int tid = threadIdx.x; int wv = tid>>6, lane = tid&63;
    int base = blockIdx.x * 16;

    for (int idx = tid; idx < 128*128; idx += 128) {
        int i = idx >> 7, d = idx & 127;
        ((bf16*)sW)[d*130 + i] = f2b(W1[idx]);
    }
    __syncthreads();
    for (int ei = 0; ei < 16; ++ei) {
        int e = base + ei; if (e >= E) break;
        sX[tid] = h_bond[(size_t)e*128 + tid];
        __syncthreads();
        float acc = B1[tid];
        const u32* wrow = &sW[tid*65];
        #pragma unroll 8
        for (int j = 0; j < 64; ++j) {
            u32 w = wrow[j];
            acc += sX[2*j]*lo16(w) + sX[2*j+1]*hi16(w);
        }
        float s1 = acc, s2 = acc*acc;
        for (int m = 1; m < 64; m <<= 1) { s1 += __shfl_xor(s1, m, 64); s2 += __shfl_xor(s2, m, 64); }
        if (lane == 0) { sRed[wv*2] = s1; sRed[wv*2+1] = s2; }
        __syncthreads();
        float tot = sRed[0] + sRed[2], tot2 = sRed[1] + sRed[3];
        float mu = tot * (1.f/128.f);
        float var = fmaxf(tot2 * (1.f/128.f) - mu*mu, 0.f);
        float nv = G[tid] * (acc - mu) * rsqrtf(var + 1e-5f) + Bln[tid];
        sH[ei][tid] = fmaxf(nv, 0.f);
        __syncthreads();
    }
    __syncthreads();
    for (int idx = tid; idx < 128*128; idx += 128) {
        int i = idx >> 7, d = idx & 127;
        ((bf16*)sW)[d*130 + i] = f2b(W2[idx]);
    }
    __syncthreads();
    for (int ei = 0; ei < 16; ++ei) {
        int e = base + ei; if (e >= E) break;
        float acc = B2[tid];
        const u32* wrow = &sW[tid*65];
        #pragma unroll 8
        for (int j = 0; j < 64; ++j) {
            u32 w = wrow[j];
            acc += sH[ei][2*j]*lo16(w) + sH[ei][2*j+1]*hi16(w);
        }
        qout[(size_t)e*128 + tid] = f2b(acc);
    }
}

// ---------------- P1[e] = h_bond[e]@W1[0:128] + rfeat[e]@W1[128:148] -> bf16 --
__global__ __launch_bounds__(128) void p_prep(
    const float* __restrict__ W1, const float* __restrict__ h_bond,
    const float* __restrict__ pos, const int* __restrict__ row,
    const int* __restrict__ col, bf16* __restrict__ P1, int E)
{
    __shared__ u32 sW[128*75];       // [dim][row-pair], 148 rows -> 74 pairs, stride 150 bf16
    __shared__ float sX[148];
    int tid = threadIdx.x;
    for (int idx = tid; idx < 148*128; idx += 128) {
        int i = idx >> 7, d = idx & 127;
        ((bf16*)sW)[d*150 + i] = f2b(W1[idx]);
    }
    __syncthreads();
    int base = blockIdx.x * 16;
    for (int ei = 0; ei < 16; ++ei) {
        int e = base + ei; if (e >= E) break;
        sX[tid] = h_bond[(size_t)e*128 + tid];
        if (tid < 20) {
            int i0 = col[e], j0 = row[e];
            float dx = pos[(size_t)i0*3+0] - pos[(size_t)j0*3+0];
            float dy = pos[(size_t)i0*3+1] - pos[(size_t)j0*3+1];
            float dz = pos[(size_t)i0*3+2] - pos[(size_t)j0*3+2];
            float dist = sqrtf(dx*dx + dy*dy + dz*dz);
            const float step = 10.0f/19.0f;
            float t = dist - (float)tid * step;
            sX[128 + tid] = expf((-0.5f/(step*step)) * t * t);
        }
        __syncthreads();
        float acc = 0.f;
        const u32* wrow = &sW[tid*75];
        #pragma unroll 8
        for (int j = 0; j < 74; ++j) {
            u32 w = wrow[j];
            acc += sX[2*j]*lo16(w) + sX[2*j+1]*hi16(w);
        }
        P1[(size_t)e*128 + tid] = f2b(acc);
        __syncthreads();
    }
}

// ======== shared per-triplet macros (2-way software pipeline) ========
// requires in scope: idx_kj, idx_k, p1u, pos, lane, pix,piy,piz, ax,ay,az,
//                    P2a, P2b, wa[13] (packed bf16 pairs of W1 rows 168..180)
#define GEOM(S, TV) \
    const int kj##S = __builtin_amdgcn_readfirstlane(idx_kj[TV]); \
    const int kn##S = __builtin_amdgcn_readfirstlane(idx_k[TV]); \
    const u32 pp##S = p1u[(size_t)kj##S*64 + lane]; \
    const float bx##S = pos[(size_t)kn##S*3+0]-pix; \
    const float by##S = pos[(size_t)kn##S*3+1]-piy; \
    const float bz##S = pos[(size_t)kn##S*3+2]-piz; \
    const float dt##S = ax*bx##S + ay*by##S + az*bz##S; \
    const float cxv##S = ay*bz##S - az*by##S; \
    const float cyv##S = az*bx##S - ax*bz##S; \
    const float czv##S = ax*by##S - ay*bx##S; \
    const float bcr##S = sqrtf(cxv##S*cxv##S + cyv##S*cyv##S + czv##S*czv##S); \
    const float ang##S = atan2f(bcr##S, dt##S); \
    float s1f##S, c1f##S, shf##S, chf##S, st3f##S, ct3f##S; \
    sincosf(ang##S, &s1f##S, &c1f##S); \
    sincosf(0.5f*ang##S, &shf##S, &chf##S); \
    sincosf((1.0f/3.0f)*ang##S, &st3f##S, &ct3f##S); \
    const float s2f##S = 2.f*s1f##S*c1f##S; \
    const float c2f##S = 1.f - 2.f*s1f##S*s1f##S; \
    const float s3f##S = s1f##S*(3.f - 4.f*s1f##S*s1f##S); \
    const float c3f##S = c1f##S*(4.f*c1f##S*c1f##S - 3.f); \
    float v0##S = P2a + lo16(pp##S); \
    float v1##S = P2b + hi16(pp##S); \
    { const float afv_[13] = {ang##S, s1f##S, s2f##S, s3f##S, s1f##S, shf##S, st3f##S, \
                              c1f##S, c2f##S, c3f##S, c1f##S, chf##S, ct3f##S}; \
      _Pragma("unroll") \
      for (int f_ = 0; f_ < 13; ++f_) { u32 w_ = wa[f_]; v0##S += afv_[f_]*lo16(w_); v1##S += afv_[f_]*hi16(w_); } }

// interleaved LayerNorm stats + apply for both chains (7 shfls each, overlapped)
#define LNPAIR() \
    float sumA = v0A + v1A, ssqA = v0A*v0A + v1A*v1A; \
    float sumB = v0B + v1B, ssqB = v0B*v0B + v1B*v1B; \
    float rA = ((lane&1) ? ssqA : sumA) + __shfl_xor((lane&1) ? sumA : ssqA, 1, 64); \
    float rB = ((lane&1) ? ssqB : sumB) + __shfl_xor((lane&1) ? sumB : ssqB, 1, 64); \
    rA += __shfl_xor(rA, 2, 64);  rB += __shfl_xor(rB, 2, 64); \
    rA += __shfl_xor(rA, 4, 64);  rB += __shfl_xor(rB, 4, 64); \
    rA += __shfl_xor(rA, 8, 64);  rB += __shfl_xor(rB, 8, 64); \
    rA += __shfl_xor(rA, 16, 64); rB += __shfl_xor(rB, 16, 64); \
    rA += __shfl_xor(rA, 32, 64); rB += __shfl_xor(rB, 32, 64); \
    float otherA = __shfl_xor(rA, 1, 64); \
    float otherB = __shfl_xor(rB, 1, 64); \
    float totA  = (lane&1) ? otherA : rA; \
    float tot2A = (lane&1) ? rA : otherA; \
    float totB  = (lane&1) ? otherB : rB; \
    float tot2B = (lane&1) ? rB : otherB; \
    float muA = totA * (1.f/128.f); \
    float muB = totB * (1.f/128.f); \
    float varA = fmaxf(tot2A * (1.f/128.f) - muA*muA, 0.f); \
    float varB = fmaxf(tot2B * (1.f/128.f) - muB*muB, 0.f); \
    float rsA = rsqrtf(varA + 1e-5f); \
    float rsB = rsqrtf(varB + 1e-5f); \
    float h0A = fmaxf(gv.x*(v0A-muA)*rsA + bv.x, 0.f); \
    float h1A = fmaxf(gv.y*(v1A-muA)*rsA + bv.y, 0.f); \
    float h0B = fmaxf(gv.x*(v0B-muB)*rsB + bv.x, 0.f); \
    float h1B = fmaxf(gv.y*(v1B-muB)*rsB + bv.y, 0.f);

// per-edge setup: P2 from global Wb rows (148..167) + wa regs (rows 168..180)
#define EDGE_P2_WA(W1full) \
    float dxx = pix-pjx, dyy = piy-pjy, dzz = piz-pjz; \
    float dist = sqrtf(dxx*dxx + dyy*dyy + dzz*dzz); \
    float P2a = b1v.x, P2b = b1v.y; \
    { const float2* wbp = (const float2*)((W1full) + (size_t)148*128); \
      const float step = 10.0f/19.0f, coef = -0.5f/(step*step); \
      for (int g2 = 0; g2 < 20; ++g2) { \
        float tg = dist - (float)g2 * step; \
        float rf = expf(coef * tg * tg); \
        float2 wb = wbp[g2*64 + lane]; \
        P2a += rf * wb.x; \
        P2b += rf * wb.y; \
      } } \
    u32 wa[13]; \
    { const float2* wap = (const float2*)((W1full) + (size_t)168*128); \
      _Pragma("unroll") \
      for (int f_ = 0; f_ < 13; ++f_) { \
        float2 w = wap[f_*64 + lane]; \
        wa[f_] = bfbits(w.x) | (bfbits(w.y) << 16); \
      } }

// ---------------- logits: wave-per-edge, raw logits out ----------------
template<int AF32>
__global__ __launch_bounds__(256, 4) void logits_kernel(
    const float* __restrict__ Wk2, const float* __restrict__ W1full,
    const float* __restrict__ B1, const float* __restrict__ G, const float* __restrict__ Bln,
    const bf16* __restrict__ qf, const bf16* __restrict__ P1k,
    const float* __restrict__ pos, const int* __restrict__ seg,
    const int* __restrict__ idx_kj, const int* __restrict__ idx_k,
    const int* __restrict__ row, const int* __restrict__ col,
    void* __restrict__ alpha, int E)
{
    // Wk2 transposed, pair-packed: word[c*65 + p] = (Wk2[2p][c], Wk2[2p+1][c]).
    // stride 65 -> coalesced global reads at staging AND conflict-free ds_write/ds_read.
    __shared__ u32 sW2T[128*65];     // 33280 B -> 4 blocks/CU
    int tid = threadIdx.x;
    for (int idx = tid; idx < 128*64; idx += 256) {
        int p = idx >> 7, c = idx & 127;
        float w0 = Wk2[(size_t)(2*p)*128 + c];
        float w1 = Wk2[(size_t)(2*p+1)*128 + c];
        sW2T[c*65 + p] = bfbits(w0) | (bfbits(w1) << 16);
    }
    __syncthreads();

    int lane = tid & 63;
    int e = __builtin_amdgcn_readfirstlane(blockIdx.x*4 + (tid>>6));
    if (e >= E) return;
    int s0 = __builtin_amdgcn_readfirstlane(seg[e]);
    int s1 = __builtin_amdgcn_readfirstlane(seg[e+1]);
    if (s1 <= s0) return;

    float2 b1v = ((const float2*)B1)[lane];
    float2 gv  = ((const float2*)G)[lane];
    float2 bv  = ((const float2*)Bln)[lane];
    int i0 = __builtin_amdgcn_readfirstlane(col[e]);
    int j0 = __builtin_amdgcn_readfirstlane(row[e]);
    float pix = pos[(size_t)i0*3+0], piy = pos[(size_t)i0*3+1], piz = pos[(size_t)i0*3+2];
    float pjx = pos[(size_t)j0*3+0], pjy = pos[(size_t)j0*3+1], pjz = pos[(size_t)j0*3+2];

    EDGE_P2_WA(W1full);

    // Gk[h][d0/d1] = sum_c-in-head q[c] * Wk2[d][c]
    float Gk0[16], Gk1[16];
    const u32* qrow = (const u32*)(qf + (size_t)e*128);
    #pragma unroll
    for (int h = 0; h < 16; ++h) {
        float g0 = 0.f, g1 = 0.f;
        #pragma unroll
        for (int j = 0; j < 4; ++j) {
            u32 qp = qrow[h*4 + j];
            float ql = lo16(qp), qh = hi16(qp);
            u32 w0 = sW2T[(h*8 + 2*j)*65 + lane];
            u32 w1 = sW2T[(h*8 + 2*j + 1)*65 + lane];
            g0 += ql*lo16(w0) + qh*lo16(w1);
            g1 += ql*hi16(w0) + qh*hi16(w1);
        }
        Gk0[h] = g0; Gk1[h] = g1;
    }

    const u32* p1u = (const u32*)P1k;
    float ax = pjx-pix, ay = pjy-piy, az = pjz-piz;
    const int hperm = ((lane&1)<<3) | ((lane&2)<<1) | ((lane&4)>>1) | ((lane&8)>>3);

    for (int t = s0; t < s1; t += 2) {
        const int tA = t;
        const int tB = (t+1 < s1) ? (t+1) : t;   // duplicate tail: benign double-store
        GEOM(A, tA);
        GEOM(B, tB);
        LNPAIR();
        float pA[16], pB[16];
        #pragma unroll
        for (int h = 0; h < 16; ++h) {
            pA[h] = h0A*Gk0[h] + h1A*Gk1[h];
            pB[h] = h0B*Gk0[h] + h1B*Gk1[h];
        }
        // split-exchange butterfly: 16 values over 64 lanes in 17 shfls, A/B interleaved
        float a8A[8], a8B[8];
        { int up = lane & 1;
          #pragma unroll
          for (int i = 0; i < 8; ++i) {
            float kpA = up ? pA[i+8] : pA[i];
            float sdA = up ? pA[i]   : pA[i+8];
            a8A[i] = kpA + __shfl_xor(sdA, 1, 64);
            float kpB = up ? pB[i+8] : pB[i];
            float sdB = up ? pB[i]   : pB[i+8];
            a8B[i] = kpB + __shfl_xor(sdB, 1, 64);
          } }
        float a4A[4], a4B[4];
        { int up = lane & 2;
          #pragma unroll
          for (int i = 0; i < 4; ++i) {
            float kpA = up ? a8A[i+4] : a8A[i];
            float sdA = up ? a8A[i]   : a8A[i+4];
            a4A[i] = kpA + __shfl_xor(sdA, 2, 64);
            float kpB = up ? a8B[i+4] : a8B[i];
            float sdB = up ? a8B[i]   : a8B[i+4];
            a4B[i] = kpB + __shfl_xor(sdB, 2, 64);
          } }
        float a2A[2], a2B[2];
        { int up = lane & 4;
          #pragma unroll
          for (int i = 0; i < 2; ++i) {
            float kpA = up ? a4A[i+2] : a4A[i];
            float sdA = up ? a4A[i]   : a4A[i+2];
            a2A[i] = kpA + __shfl_xor(sdA, 4, 64);
            float kpB = up ? a4B[i+2] : a4B[i];
            float sdB = up ? a4B[i]   : a4B[i+2];
            a2B[i] = kpB + __shfl_xor(sdB, 4, 64);
          } }
        float a1A, a1B;
        { int up = lane & 8;
          float kpA = up ? a2A[1] : a2A[0];
          float sdA = up ? a2A[0] : a2A[1];
          a1A = kpA + __shfl_xor(sdA, 8, 64);
          float kpB = up ? a2B[1] : a2B[0];
          float sdB = up ? a2B[0] : a2B[1];
          a1B = kpB + __shfl_xor(sdB, 8, 64);
        }
        a1A += __shfl_xor(a1A, 16, 64);  a1B += __shfl_xor(a1B, 16, 64);
        a1A += __shfl_xor(a1A, 32, 64);  a1B += __shfl_xor(a1B, 32, 64);
        if (lane < 16) {
            float lgA = a1A * RSQRT8;
            float lgB = a1B * RSQRT8;
            if (AF32) {
                ((float*)alpha)[(size_t)tA*16 + hperm] = lgA;
                ((float*)alpha)[(size_t)tB*16 + hperm] = lgB;
            } else {
                ((bf16*)alpha)[(size_t)tA*16 + hperm] = f2b(lgA);
                ((bf16*)alpha)[(size_t)tB*16 + hperm] = f2b(lgB);
            }
        }
    }
}

// ---------------- out: wave-per-edge, fused softmax + v-path + projection ----
template<int AF32>
__global__ __launch_bounds__(256, 3) void out_kernel(
    const float* __restrict__ Wv2, const float* __restrict__ B2v,
    const float* __restrict__ W1full, const float* __restrict__ B1,
    const float* __restrict__ G, const float* __restrict__ Bln,
    const bf16* __restrict__ P1v, const float* __restrict__ pos,
    void* __restrict__ alpha, const int* __restrict__ seg,
    const int* __restrict__ idx_kj, const int* __restrict__ idx_k,
    const int* __restrict__ row, const int* __restrict__ col,
    float* __restrict__ out, int E)
{
    __shared__ u32 sW2[128*65];      // Wv2 transposed [o][d-pair], stride 130 bf16
    __shared__ u32 sS[4][16*66];     // per-wave S bf16 pairs: [h][d-pair j], stride 66
    int tid = threadIdx.x;
    for (int idx = tid; idx < 128*128; idx += 256) {
        int d = idx >> 7, o = idx & 127;
        ((bf16*)sW2)[o*130 + d] = f2b(Wv2[(size_t)d*128 + o]);
    }
    __syncthreads();

    int lane = tid & 63, wv = tid >> 6;
    int e = __builtin_amdgcn_readfirstlane(blockIdx.x*4 + wv);
    if (e >= E) return;
    int s0 = __builtin_amdgcn_readfirstlane(seg[e]);
    int s1 = __builtin_amdgcn_readfirstlane(seg[e+1]);
    if (s1 <= s0) { out[(size_t)e*128 + lane] = 0.f; out[(size_t)e*128 + 64 + lane] = 0.f; return; }

    // ---- segment softmax prepass, all 64 lanes: lane = tt*16 + h handles
    // triplets t = s0+tt, s0+tt+4, ...  Stores UNNORMALIZED exp; 1/sum folded
    // into the final S scaling (removes the normalize write-back pass).
    float inv;
    {
        int h = lane & 15, tt = lane >> 4;
        float m = -3.4e38f;
        for (int t = s0 + tt; t < s1; t += 4) {
            float x = AF32 ? ((const float*)alpha)[(size_t)t*16 + h]
                           : b2f(((const bf16*)alpha)[(size_t)t*16 + h]);
            m = fmaxf(m, x);
        }
        m = fmaxf(m, __shfl_xor(m, 16, 64));
        m = fmaxf(m, __shfl_xor(m, 32, 64));
        float s = 0.f;
        for (int t = s0 + tt; t < s1; t += 4) {
            float x = AF32 ? ((const float*)alpha)[(size_t)t*16 + h]
                           : b2f(((const bf16*)alpha)[(size_t)t*16 + h]);
            float ex = expf(x - m);
            s += ex;
            if (AF32) ((float*)alpha)[(size_t)t*16 + h] = ex;
            else      ((bf16*)alpha)[(size_t)t*16 + h] = f2b(ex);
        }
        s += __shfl_xor(s, 16, 64);
        s += __shfl_xor(s, 32, 64);
        inv = 1.f / s;               // lane l holds inv for head l&15
    }

    float2 b1v = ((const float2*)B1)[lane];
    float2 gv  = ((const float2*)G)[lane];
    float2 bv  = ((const float2*)Bln)[lane];
    int i0 = __builtin_amdgcn_readfirstlane(col[e]);
    int j0 = __builtin_amdgcn_readfirstlane(row[e]);
    float pix = pos[(size_t)i0*3+0], piy = pos[(size_t)i0*3+1], piz = pos[(size_t)i0*3+2];
    float pjx = pos[(size_t)j0*3+0], pjy = pos[(size_t)j0*3+1], pjz = pos[(size_t)j0*3+2];

    EDGE_P2_WA(W1full);

    float S0[16], S1[16];
    #pragma unroll
    for (int h = 0; h < 16; ++h) { S0[h] = 0.f; S1[h] = 0.f; }

    const u32* p1u = (const u32*)P1v;
    float ax = pjx-pix, ay = pjy-piy, az = pjz-piz;
    for (int t = s0; t < s1; t += 2) {
        const int tA = t;
        const bool twoB = (t+1 < s1);
        const int tB = twoB ? (t+1) : t;
        // issue alpha (exp) loads early — independent of geometry chains
        float alA[16], alB[16];
        if (AF32) {
            const float* apA = (const float*)alpha + (size_t)tA*16;
            const float* apB = (const float*)alpha + (size_t)tB*16;
            #pragma unroll
            for (int h = 0; h < 16; ++h) { alA[h] = apA[h]; alB[h] = apB[h]; }
        } else {
            const u32* apA = (const u32*)((const bf16*)alpha + (size_t)tA*16);
            const u32* apB = (const u32*)((const bf16*)alpha + (size_t)tB*16);
            #pragma unroll
            for (int j = 0; j < 8; ++j) {
                u32 uA = apA[j]; alA[2*j] = lo16(uA); alA[2*j+1] = hi16(uA);
                u32 uB = apB[j]; alB[2*j] = lo16(uB); alB[2*j+1] = hi16(uB);
            }
        }
        GEOM(A, tA);
        GEOM(B, tB);
        LNPAIR();
        #pragma unroll
        for (int h = 0; h < 16; ++h) { S0[h] += alA[h]*h0A; S1[h] += alA[h]*h1A; }
        if (twoB) {
            #pragma unroll
            for (int h = 0; h < 16; ++h) { S0[h] += alB[h]*h0B; S1[h] += alB[h]*h1B; }
        }
    }

    // stage S as bf16 pairs, scaled by 1/denominator of each head:
    // sS[wv][h*66 + l] packs (S[h][2l], S[h][2l+1])
    #pragma unroll
    for (int h = 0; h < 16; ++h) {
        float sc = __shfl(inv, h, 64);
        sS[wv][h*66 + lane] = bfbits(S0[h]*sc) | (bfbits(S1[h]*sc) << 16);
    }
    __threadfence_block();
    // projection: out[o] = sum_d S[o>>3][d]*Wv2[d][o] + bv2[o];  o0=lane, o1=lane+64
    int h0i = lane >> 3, h1i = 8 + (lane >> 3);
    float acc0 = B2v[lane], acc1 = B2v[lane + 64];
    const u32* sr0 = &sS[wv][h0i*66];
    const u32* sr1 = &sS[wv][h1i*66];
    const u32* wr0 = &sW2[lane*65];
    const u32* wr1 = &sW2[(lane+64)*65];
    #pragma unroll 8
    for (int j = 0; j < 64; ++j) {
        u32 us0 = sr0[j], uw0 = wr0[j];
        u32 us1 = sr1[j], uw1 = wr1[j];
        acc0 += lo16(us0)*lo16(uw0) + hi16(us0)*hi16(uw0);
        acc1 += lo16(us1)*lo16(uw1) + hi16(us1)*hi16(uw1);
    }
    out[(size_t)e*128 + lane] = acc0;
    out[(size_t)e*128 + 64 + lane] = acc1;
}

extern "C" void kernel_launch(void* const* d_in, const int* in_sizes, int n_in,
                              void* d_out, int out_size, void* d_ws, size_t ws_size,
                              hipStream_t stream)
{
    const float* h_bond = (const float*)d_in[1];
    const float* pos    = (const float*)d_in[2];
    const float* hkW1 = (const float*)d_in[3];
    const float* hkb1 = (const float*)d_in[4];
    const float* hkg  = (const float*)d_in[5];
    const float* hkb  = (const float*)d_in[6];
    const float* hkW2 = (const float*)d_in[7];
    const float* hvW1 = (const float*)d_in[9];
    const float* hvb1 = (const float*)d_in[10];
    const float* hvg  = (const float*)d_in[11];
    const float* hvb  = (const float*)d_in[12];
    const float* hvW2 = (const float*)d_in[13];
    const float* hvb2 = (const float*)d_in[14];
    const float* hqW1 = (const float*)d_in[15];
    const float* hqb1 = (const float*)d_in[16];
    const float* hqg  = (const float*)d_in[17];
    const float* hqb  = (const float*)d_in[18];
    const float* hqW2 = (const float*)d_in[19];
    const float* hqb2 = (const float*)d_in[20];
    const int* row    = (const int*)d_in[21];
    const int* col    = (const int*)d_in[22];
    const int* idx_k  = (const int*)d_in[25];
    const int* idx_kj = (const int*)d_in[26];
    const int* idx_ji = (const int*)d_in[27];

    int E = in_sizes[21];
    int T = in_sizes[27];

    char* w = (char*)d_ws;
    size_t off = 0;
    auto carve = [&](size_t bytes) -> void* {
        void* p = w + off;
        off = (off + bytes + 255) & ~(size_t)255;
        return p;
    };
    int*  seg   = (int*) carve(((size_t)E + 1) * sizeof(int));
    bf16* qf    = (bf16*)carve((size_t)E * 128 * sizeof(bf16));
    bf16* P1k   = (bf16*)carve((size_t)E * 128 * sizeof(bf16));
    bf16* P1v   = (bf16*)carve((size_t)E * 128 * sizeof(bf16));
    size_t szA32 = (size_t)T * 16 * sizeof(float);
    size_t szA16 = (size_t)T * 16 * sizeof(bf16);
    int AF32 = ((off + szA32 + 255) <= ws_size) ? 1 : 0;
    void* alpha = carve(AF32 ? szA32 : szA16);

    if (off > ws_size) {
        marker_kernel<<<(out_size + 255)/256, 256, 0, stream>>>((float*)d_out, out_size);
        return;
    }

    int gq = (E + 15)/16;
    int gw = (E + 3)/4;
    seg_start_kernel<<<(E + 1 + 255)/256, 256, 0, stream>>>(idx_ji, T, seg, E);
    q_kernel<<<gq, 128, 0, stream>>>(hqW1, hqb1, hqg, hqb, hqW2, hqb2, h_bond, qf, E);
    p_prep<<<gq, 128, 0, stream>>>(hkW1, h_bond, pos, row, col, P1k, E);
    p_prep<<<gq, 128, 0, stream>>>(hvW1, h_bond, pos, row, col, P1v, E);
    if (AF32) {
        logits_kernel<1><<<gw, 256, 0, stream>>>(hkW2, hkW1, hkb1, hkg, hkb, qf, P1k, pos, seg, idx_kj, idx_k, row, col, alpha, E);
        out_kernel<1><<<gw, 256, 0, stream>>>(hvW2, hvb2, hvW1, hvb1, hvg, hvb, P1v, pos, alpha, seg, idx_kj, idx_k, row, col, (float*)d_out, E);
    } else {
        logits_kernel<0><<<gw, 256, 0, stream>>>(hkW2, hkW1, hkb1, hkg, hkb, qf, P1k, pos, seg, idx_kj, idx_k, row, col, alpha, E);
        out_kernel<0><<<gw, 256, 0, stream>>>(hvW2, hvb2, hvW1, hvb1, hvg, hvb, P1v, pos, alpha, seg, idx_kj, idx_k, row, col, (float*)d_out, E);
    }
}

// Round 3
// 1794.727 us; speedup vs baseline: 1.5767x; 1.1515x over previous
//
#include <hip/hip_runtime.h>
#include <hip/hip_bf16.h>
#include <math.h>

typedef __hip_bfloat16 bf16;
typedef unsigned int u32;

__device__ __forceinline__ float b2f(bf16 x){ return __bfloat162float(x); }
__device__ __forceinline__ bf16  f2b(float x){ return __float2bfloat16(x); }
__device__ __forceinline__ float lo16(u32 u){ return __uint_as_float(u << 16); }
__device__ __forceinline__ float hi16(u32 u){ return __uint_as_float(u & 0xFFFF0000u); }
// float -> bf16 bits with round-to-nearest-even
__device__ __forceinline__ u32 bfbits(float x){
    u32 u = __float_as_uint(x);
    return (u + 0x7FFFu + ((u >> 16) & 1u)) >> 16;
}

#define RSQRT8 0.35355339059327373f
#define G_STEP (10.0f/19.0f)
#define G_COEF (-0.5f/(G_STEP*G_STEP))

// butterfly layout involution: lane l holds head PERM4(l&15); PERM4 is self-inverse
__device__ __forceinline__ constexpr int PERM4(int h){
    return ((h&1)<<3) | ((h&2)<<1) | ((h&4)>>1) | ((h&8)>>3);
}

// fast atan2 for y >= 0 (result in [0, pi]); poly max err ~1.6e-6 rad
__device__ __forceinline__ float fast_atan2(float y, float x){
    float ax = fabsf(x);
    float mn = fminf(y, ax), mx = fmaxf(y, ax);
    float t = mn / fmaxf(mx, 1e-30f);
    float s = t*t;
    float p = t * (0.99997726f + s*(-0.33262347f + s*(0.19354346f +
              s*(-0.11643287f + s*(0.05265332f + s*(-0.01172120f))))));
    float r = (y > ax) ? (1.5707963267948966f - p) : p;
    r = (x < 0.f) ? (3.14159265358979323f - r) : r;
    return r;
}

// inputs are PROVEN f32 (R1/R2 bf16 interpretation -> NaN; R3/R4 probe-selected f32 -> pass)

// ---------------- seg starts (idx_ji sorted) ----------------
__global__ void seg_start_kernel(const int* __restrict__ idx_ji, int T,
                                 int* __restrict__ seg, int E)
{
    int e = blockIdx.x * blockDim.x + threadIdx.x;
    if (e > E) return;
    int lo = 0, hi = T;
    while (lo < hi) { int mid = (lo + hi) >> 1; if (idx_ji[mid] < e) lo = mid + 1; else hi = mid; }
    seg[e] = lo;
}

__global__ void marker_kernel(float* out, int n){
    int i = blockIdx.x * blockDim.x + threadIdx.x;
    if (i < n) out[i] = 12345.0f;
}

// ---------------- pack W2 matrices to bf16-pair layouts (L2-resident) --------
// kw2t[c*64 + p]  = (Wk2[2p][c],  Wk2[2p+1][c])   (Gk compute: lane = p)
// vw2t[j*128 + o] = (Wv2[2j][o],  Wv2[2j+1][o])   (projection: lane = o)
__global__ void pack_w2(const float* __restrict__ Wk2, const float* __restrict__ Wv2,
                        u32* __restrict__ kw2t, u32* __restrict__ vw2t)
{
    int idx = blockIdx.x*256 + threadIdx.x;
    if (idx >= 8192) return;
    int c = idx >> 6, p = idx & 63;
    kw2t[idx] = bfbits(Wk2[(size_t)(2*p)*128 + c]) | (bfbits(Wk2[(size_t)(2*p+1)*128 + c]) << 16);
    int j = idx >> 7, o = idx & 127;
    vw2t[idx] = bfbits(Wv2[(size_t)(2*j)*128 + o]) | (bfbits(Wv2[(size_t)(2*j+1)*128 + o]) << 16);
}

// ---------------- q = MLP_hq(h_bond) per edge -> bf16 ----------------
__global__ __launch_bounds__(128) void q_kernel(
    const float* __restrict__ W1, const float* __restrict__ B1,
    const float* __restrict__ G,  const float* __restrict__ Bln,
    const float* __restrict__ W2, const float* __restrict__ B2,
    const float* __restrict__ h_bond, bf16* __restrict__ qout, int E)
{
    __shared__ u32 sW[128*65];       // [dim][row-pair] packed bf16, row stride 130 bf16
    __shared__ float sH[16][130];
    __shared__ float sX[128];
    __shared__ float sRed[4];
    int tid = threadIdx.x; int wv = tid>>6, lane = tid&63;
    int base = blockIdx.x * 16;

    for (int idx = tid; idx < 128*128; idx += 128) {
        int i = idx >> 7, d = idx & 127;
        ((bf16*)sW)[d*130 + i] = f2b(W1[idx]);
    }
    __syncthreads();
    for (int ei = 0; ei < 16; ++ei) {
        int e = base + ei; if (e >= E) break;
        sX[tid] = h_bond[(size_t)e*128 + tid];
        __syncthreads();
        float acc = B1[tid];
        const u32* wrow = &sW[tid*65];
        #pragma unroll 8
        for (int j = 0; j < 64; ++j) {
            u32 w = wrow[j];
            acc += sX[2*j]*lo16(w) + sX[2*j+1]*hi16(w);
        }
        float s1 = acc, s2 = acc*acc;
        for (int m = 1; m < 64; m <<= 1) { s1 += __shfl_xor(s1, m, 64); s2 += __shfl_xor(s2, m, 64); }
        if (lane == 0) { sRed[wv*2] = s1; sRed[wv*2+1] = s2; }
        __syncthreads();
        float tot = sRed[0] + sRed[2], tot2 = sRed[1] + sRed[3];
        float mu = tot * (1.f/128.f);
        float var = fmaxf(tot2 * (1.f/128.f) - mu*mu, 0.f);
        float nv = G[tid] * (acc - mu) * rsqrtf(var + 1e-5f) + Bln[tid];
        sH[ei][tid] = fmaxf(nv, 0.f);
        __syncthreads();
    }
    __syncthreads();
    for (int idx = tid; idx < 128*128; idx += 128) {
        int i = idx >> 7, d = idx & 127;
        ((bf16*)sW)[d*130 + i] = f2b(W2[idx]);
    }
    __syncthreads();
    for (int ei = 0; ei < 16; ++ei) {
        int e = base + ei; if (e >= E) break;
        float acc = B2[tid];
        const u32* wrow = &sW[tid*65];
        #pragma unroll 8
        for (int j = 0; j < 64; ++j) {
            u32 w = wrow[j];
            acc += sH[ei][2*j]*lo16(w) + sH[ei][2*j+1]*hi16(w);
        }
        qout[(size_t)e*128 + tid] = f2b(acc);
    }
}

// ---------------- P1[e] = h_bond[e]@W1[0:128] + rfeat[e]@W1[128:148] -> bf16 --
// 4-edge batched: weight ds_reads amortized x4, 2 barriers per 4 edges, 4 indep FMA chains
__global__ __launch_bounds__(128) void p_prep(
    const float* __restrict__ W1, const float* __restrict__ h_bond,
    const float* __restrict__ pos, const int* __restrict__ row,
    const int* __restrict__ col, bf16* __restrict__ P1, int E)
{
    __shared__ u32 sW[128*75];       // [dim][row-pair], 148 rows -> 74 pairs, stride 150 bf16
    __shared__ float sX[4][152];
    int tid = threadIdx.x;
    for (int idx = tid; idx < 148*128; idx += 128) {
        int i = idx >> 7, d = idx & 127;
        ((bf16*)sW)[d*150 + i] = f2b(W1[idx]);
    }
    __syncthreads();
    int base = blockIdx.x * 16;
    for (int e4 = 0; e4 < 16; e4 += 4) {
        #pragma unroll
        for (int q = 0; q < 4; ++q) {
            int e = base + e4 + q;
            sX[q][tid] = (e < E) ? h_bond[(size_t)e*128 + tid] : 0.f;
        }
        if (tid < 80) {
            int q = tid / 20, g = tid % 20;
            int e = base + e4 + q;
            float rf = 0.f;
            if (e < E) {
                int i0 = col[e], j0 = row[e];
                float dx = pos[(size_t)i0*3+0] - pos[(size_t)j0*3+0];
                float dy = pos[(size_t)i0*3+1] - pos[(size_t)j0*3+1];
                float dz = pos[(size_t)i0*3+2] - pos[(size_t)j0*3+2];
                float dist = sqrtf(dx*dx + dy*dy + dz*dz);
                float t = dist - (float)g * G_STEP;
                rf = __expf(G_COEF * t * t);
            }
            sX[q][128 + g] = rf;
        }
        __syncthreads();
        float acc0 = 0.f, acc1 = 0.f, acc2 = 0.f, acc3 = 0.f;
        const u32* wrow = &sW[tid*75];
        #pragma unroll 4
        for (int j = 0; j < 74; ++j) {
            u32 w = wrow[j]; float wl = lo16(w), wh = hi16(w);
            acc0 += sX[0][2*j]*wl + sX[0][2*j+1]*wh;
            acc1 += sX[1][2*j]*wl + sX[1][2*j+1]*wh;
            acc2 += sX[2][2*j]*wl + sX[2][2*j+1]*wh;
            acc3 += sX[3][2*j]*wl + sX[3][2*j+1]*wh;
        }
        int e = base + e4;
        if (e   < E) P1[(size_t)e*128     + tid] = f2b(acc0);
        if (e+1 < E) P1[(size_t)(e+1)*128 + tid] = f2b(acc1);
        if (e+2 < E) P1[(size_t)(e+2)*128 + tid] = f2b(acc2);
        if (e+3 < E) P1[(size_t)(e+3)*128 + tid] = f2b(acc3);
        __syncthreads();
    }
}

// per-edge setup: P2 pre-act (gaussian part + b1) and 13 angular weight pairs in regs
#define EDGE_SETUP(W1full, b1v_, P2a_, P2b_, wa_) \
    float P2a_ = b1v_.x, P2b_ = b1v_.y; \
    { const float2* wbp = (const float2*)((W1full) + (size_t)148*128); \
      for (int g2 = 0; g2 < 20; ++g2) { \
        float tg = dist - (float)g2 * G_STEP; \
        float rf = __expf(G_COEF * tg * tg); \
        float2 wb = wbp[g2*64 + lane]; \
        P2a_ += rf * wb.x; \
        P2b_ += rf * wb.y; \
      } } \
    u32 wa_[13]; \
    { const float2* wap = (const float2*)((W1full) + (size_t)168*128); \
      _Pragma("unroll") \
      for (int f_ = 0; f_ < 13; ++f_) { \
        float2 w = wap[f_*64 + lane]; \
        wa_[f_] = bfbits(w.x) | (bfbits(w.y) << 16); \
      } }

// ---------------- fused: logits + online softmax + v-path + projection -------
// one pass over triplets; geometry/trig computed ONCE (was twice across 2 kernels);
// no alpha global round-trip; LDS = sS only (16.9KB) -> occupancy VGPR-bound
__global__ __launch_bounds__(256, 3) void fused_kernel(
    const u32* __restrict__ kw2t, const u32* __restrict__ vw2t,
    const float* __restrict__ Wk1, const float* __restrict__ Bk1,
    const float* __restrict__ Gkg, const float* __restrict__ Bkln,
    const float* __restrict__ Wv1, const float* __restrict__ Bv1,
    const float* __restrict__ Gvg, const float* __restrict__ Bvln,
    const float* __restrict__ B2v,
    const bf16* __restrict__ qf, const bf16* __restrict__ P1k, const bf16* __restrict__ P1v,
    const float* __restrict__ pos, const int* __restrict__ seg,
    const int* __restrict__ idx_kj, const int* __restrict__ idx_k,
    const int* __restrict__ row, const int* __restrict__ col,
    float* __restrict__ out, int E)
{
    __shared__ u32 sS[4][16*66];     // per-wave S bf16 pairs: [h][d-pair], stride 66
    int tid = threadIdx.x, lane = tid & 63, wv = tid >> 6;
    int e = __builtin_amdgcn_readfirstlane(blockIdx.x*4 + wv);
    if (e >= E) return;
    int s0 = __builtin_amdgcn_readfirstlane(seg[e]);
    int s1 = __builtin_amdgcn_readfirstlane(seg[e+1]);
    if (s1 <= s0) { out[(size_t)e*128 + lane] = 0.f; out[(size_t)e*128 + 64 + lane] = 0.f; return; }

    float2 b1k = ((const float2*)Bk1)[lane];
    float2 gk  = ((const float2*)Gkg)[lane];
    float2 bk  = ((const float2*)Bkln)[lane];
    float2 b1v = ((const float2*)Bv1)[lane];
    float2 gv  = ((const float2*)Gvg)[lane];
    float2 bv  = ((const float2*)Bvln)[lane];

    int i0 = __builtin_amdgcn_readfirstlane(col[e]);
    int j0 = __builtin_amdgcn_readfirstlane(row[e]);
    float pix = pos[(size_t)i0*3+0], piy = pos[(size_t)i0*3+1], piz = pos[(size_t)i0*3+2];
    float pjx = pos[(size_t)j0*3+0], pjy = pos[(size_t)j0*3+1], pjz = pos[(size_t)j0*3+2];
    float dxx = pix-pjx, dyy = piy-pjy, dzz = piz-pjz;
    float dist = sqrtf(dxx*dxx + dyy*dyy + dzz*dzz);

    EDGE_SETUP(Wk1, b1k, P2ak, P2bk, wak);
    EDGE_SETUP(Wv1, b1v, P2av, P2bv, wav);

    // Gk[h][2*lane(+1)] = sum_{c in head h} q[c] * Wk2[d][c]  (weights from global, L2-hot)
    float Gk0[16], Gk1[16];
    const u32* qrow = (const u32*)(qf + (size_t)e*128);
    #pragma unroll
    for (int h = 0; h < 16; ++h) {
        float g0 = 0.f, g1 = 0.f;
        #pragma unroll
        for (int j = 0; j < 4; ++j) {
            u32 qp = qrow[h*4 + j];
            float ql = lo16(qp), qh = hi16(qp);
            u32 w0 = kw2t[(h*8 + 2*j)*64 + lane];
            u32 w1 = kw2t[(h*8 + 2*j + 1)*64 + lane];
            g0 += ql*lo16(w0) + qh*lo16(w1);
            g1 += ql*hi16(w0) + qh*hi16(w1);
        }
        Gk0[h] = g0; Gk1[h] = g1;
    }

    float S0[16], S1[16];
    #pragma unroll
    for (int h = 0; h < 16; ++h) { S0[h] = 0.f; S1[h] = 0.f; }
    float m = -1e30f, sden = 0.f;

    const u32* p1ku = (const u32*)P1k;
    const u32* p1vu = (const u32*)P1v;
    float ax = pjx-pix, ay = pjy-piy, az = pjz-piz;

    // software prefetch rotation (indices -> P1 rows -> pos) one triplet ahead
    int kj_p = __builtin_amdgcn_readfirstlane(idx_kj[s0]);
    int kn_p = __builtin_amdgcn_readfirstlane(idx_k[s0]);
    u32 ppk_p = p1ku[(size_t)kj_p*64 + lane];
    u32 ppv_p = p1vu[(size_t)kj_p*64 + lane];
    float pkx = pos[(size_t)kn_p*3+0], pky = pos[(size_t)kn_p*3+1], pkz = pos[(size_t)kn_p*3+2];

    for (int t = s0; t < s1; ++t) {
        u32 ppk = ppk_p, ppv = ppv_p;
        float bx = pkx-pix, by = pky-piy, bz = pkz-piz;
        int tn = (t+1 < s1) ? (t+1) : t;
        kj_p = __builtin_amdgcn_readfirstlane(idx_kj[tn]);
        kn_p = __builtin_amdgcn_readfirstlane(idx_k[tn]);
        ppk_p = p1ku[(size_t)kj_p*64 + lane];
        ppv_p = p1vu[(size_t)kj_p*64 + lane];
        pkx = pos[(size_t)kn_p*3+0]; pky = pos[(size_t)kn_p*3+1]; pkz = pos[(size_t)kn_p*3+2];

        // geometry + fast trig (once per triplet; was computed twice pre-fusion)
        float dt = ax*bx + ay*by + az*bz;
        float cx = ay*bz - az*by, cy = az*bx - ax*bz, cz = ax*by - ay*bx;
        float bcr = sqrtf(cx*cx + cy*cy + cz*cz);
        float ang = fast_atan2(bcr, dt);
        float s1a = __sinf(ang),          c1a = __cosf(ang);
        float sh  = __sinf(0.5f*ang),     ch  = __cosf(0.5f*ang);
        float st3 = __sinf((1.f/3.f)*ang), ct3 = __cosf((1.f/3.f)*ang);
        float s2a = 2.f*s1a*c1a, c2a = 1.f - 2.f*s1a*s1a;
        float s3a = s1a*(3.f - 4.f*s1a*s1a), c3a = c1a*(4.f*c1a*c1a - 3.f);
        float af[13] = {ang, s1a, s2a, s3a, s1a, sh, st3, c1a, c2a, c3a, c1a, ch, ct3};

        // pre-activations, k-path (A) and v-path (B)
        float v0A = P2ak + lo16(ppk), v1A = P2bk + hi16(ppk);
        float v0B = P2av + lo16(ppv), v1B = P2bv + hi16(ppv);
        #pragma unroll
        for (int f = 0; f < 13; ++f) {
            u32 wkp = wak[f], wvp = wav[f];
            v0A += af[f]*lo16(wkp); v1A += af[f]*hi16(wkp);
            v0B += af[f]*lo16(wvp); v1B += af[f]*hi16(wvp);
        }
        // both LayerNorms, interleaved 7-shfl split reductions
        float sumA = v0A + v1A, ssqA = v0A*v0A + v1A*v1A;
        float sumB = v0B + v1B, ssqB = v0B*v0B + v1B*v1B;
        float rA = ((lane&1) ? ssqA : sumA) + __shfl_xor((lane&1) ? sumA : ssqA, 1, 64);
        float rB = ((lane&1) ? ssqB : sumB) + __shfl_xor((lane&1) ? sumB : ssqB, 1, 64);
        rA += __shfl_xor(rA, 2, 64);  rB += __shfl_xor(rB, 2, 64);
        rA += __shfl_xor(rA, 4, 64);  rB += __shfl_xor(rB, 4, 64);
        rA += __shfl_xor(rA, 8, 64);  rB += __shfl_xor(rB, 8, 64);
        rA += __shfl_xor(rA, 16, 64); rB += __shfl_xor(rB, 16, 64);
        rA += __shfl_xor(rA, 32, 64); rB += __shfl_xor(rB, 32, 64);
        float oA = __shfl_xor(rA, 1, 64), oB = __shfl_xor(rB, 1, 64);
        float totA  = (lane&1) ? oA : rA, tot2A = (lane&1) ? rA : oA;
        float totB  = (lane&1) ? oB : rB, tot2B = (lane&1) ? rB : oB;
        float muA = totA * (1.f/128.f);
        float muB = totB * (1.f/128.f);
        float varA = fmaxf(tot2A * (1.f/128.f) - muA*muA, 0.f);
        float varB = fmaxf(tot2B * (1.f/128.f) - muB*muB, 0.f);
        float rsA = rsqrtf(varA + 1e-5f), rsB = rsqrtf(varB + 1e-5f);
        float h0A = fmaxf(gk.x*(v0A-muA)*rsA + bk.x, 0.f);
        float h1A = fmaxf(gk.y*(v1A-muA)*rsA + bk.y, 0.f);
        float h0B = fmaxf(gv.x*(v0B-muB)*rsB + bv.x, 0.f);
        float h1B = fmaxf(gv.y*(v1B-muB)*rsB + bv.y, 0.f);

        // logits: per-head partials then 17-shfl split-exchange butterfly
        float p[16];
        #pragma unroll
        for (int h = 0; h < 16; ++h) p[h] = h0A*Gk0[h] + h1A*Gk1[h];
        float a8[8];
        { int up = lane & 1;
          #pragma unroll
          for (int i = 0; i < 8; ++i) {
            float kp = up ? p[i+8] : p[i];
            float sd = up ? p[i]   : p[i+8];
            a8[i] = kp + __shfl_xor(sd, 1, 64);
          } }
        float a4[4];
        { int up = lane & 2;
          #pragma unroll
          for (int i = 0; i < 4; ++i) {
            float kp = up ? a8[i+4] : a8[i];
            float sd = up ? a8[i]   : a8[i+4];
            a4[i] = kp + __shfl_xor(sd, 2, 64);
          } }
        float a2[2];
        { int up = lane & 4;
          #pragma unroll
          for (int i = 0; i < 2; ++i) {
            float kp = up ? a4[i+2] : a4[i];
            float sd = up ? a4[i]   : a4[i+2];
            a2[i] = kp + __shfl_xor(sd, 4, 64);
          } }
        float a1;
        { int up = lane & 8;
          float kp = up ? a2[1] : a2[0];
          float sd = up ? a2[0] : a2[1];
          a1 = kp + __shfl_xor(sd, 8, 64);
        }
        a1 += __shfl_xor(a1, 16, 64);
        a1 += __shfl_xor(a1, 32, 64);
        float lg = a1 * RSQRT8;      // lane l: logit for head PERM4(l&15)

        // online softmax with defer-max (rescale only when max grows > 8)
        if (__any(lg > m + 8.f)) {
            float nm = fmaxf(m, lg);
            float fac = __expf(m - nm);
            sden *= fac; m = nm;
            #pragma unroll
            for (int h = 0; h < 16; ++h) {
                float fh = __shfl(fac, PERM4(h), 64);
                S0[h] *= fh; S1[h] *= fh;
            }
        }
        float ex = __expf(lg - m);
        sden += ex;
        #pragma unroll
        for (int h = 0; h < 16; ++h) {
            float alh = __shfl(ex, PERM4(h), 64);
            S0[h] += alh*h0B; S1[h] += alh*h1B;
        }
    }

    // normalize by softmax denominator while staging S as bf16 pairs
    float inv = 1.f / sden;
    #pragma unroll
    for (int h = 0; h < 16; ++h) {
        float sc = __shfl(inv, PERM4(h), 64);
        sS[wv][h*66 + lane] = bfbits(S0[h]*sc) | (bfbits(S1[h]*sc) << 16);
    }
    __threadfence_block();
    // projection: out[o] = sum_d S[o>>3][d]*Wv2[d][o] + b2[o];  o0=lane, o1=lane+64
    int h0i = lane >> 3, h1i = 8 + (lane >> 3);
    float acc0 = B2v[lane], acc1 = B2v[lane + 64];
    const u32* sr0 = &sS[wv][h0i*66];
    const u32* sr1 = &sS[wv][h1i*66];
    #pragma unroll 8
    for (int j = 0; j < 64; ++j) {
        u32 us0 = sr0[j], uw0 = vw2t[j*128 + lane];
        u32 us1 = sr1[j], uw1 = vw2t[j*128 + 64 + lane];
        acc0 += lo16(us0)*lo16(uw0) + hi16(us0)*hi16(uw0);
        acc1 += lo16(us1)*lo16(uw1) + hi16(us1)*hi16(uw1);
    }
    out[(size_t)e*128 + lane] = acc0;
    out[(size_t)e*128 + 64 + lane] = acc1;
}

extern "C" void kernel_launch(void* const* d_in, const int* in_sizes, int n_in,
                              void* d_out, int out_size, void* d_ws, size_t ws_size,
                              hipStream_t stream)
{
    const float* h_bond = (const float*)d_in[1];
    const float* pos    = (const float*)d_in[2];
    const float* hkW1 = (const float*)d_in[3];
    const float* hkb1 = (const float*)d_in[4];
    const float* hkg  = (const float*)d_in[5];
    const float* hkb  = (const float*)d_in[6];
    const float* hkW2 = (const float*)d_in[7];
    const float* hvW1 = (const float*)d_in[9];
    const float* hvb1 = (const float*)d_in[10];
    const float* hvg  = (const float*)d_in[11];
    const float* hvb  = (const float*)d_in[12];
    const float* hvW2 = (const float*)d_in[13];
    const float* hvb2 = (const float*)d_in[14];
    const float* hqW1 = (const float*)d_in[15];
    const float* hqb1 = (const float*)d_in[16];
    const float* hqg  = (const float*)d_in[17];
    const float* hqb  = (const float*)d_in[18];
    const float* hqW2 = (const float*)d_in[19];
    const float* hqb2 = (const float*)d_in[20];
    const int* row    = (const int*)d_in[21];
    const int* col    = (const int*)d_in[22];
    const int* idx_k  = (const int*)d_in[25];
    const int* idx_kj = (const int*)d_in[26];
    const int* idx_ji = (const int*)d_in[27];

    int E = in_sizes[21];
    int T = in_sizes[27];

    char* w = (char*)d_ws;
    size_t off = 0;
    auto carve = [&](size_t bytes) -> void* {
        void* p = w + off;
        off = (off + bytes + 255) & ~(size_t)255;
        return p;
    };
    int*  seg   = (int*) carve(((size_t)E + 1) * sizeof(int));
    bf16* qf    = (bf16*)carve((size_t)E * 128 * sizeof(bf16));
    bf16* P1k   = (bf16*)carve((size_t)E * 128 * sizeof(bf16));
    bf16* P1v   = (bf16*)carve((size_t)E * 128 * sizeof(bf16));
    u32*  kw2t  = (u32*) carve(8192 * sizeof(u32));
    u32*  vw2t  = (u32*) carve(8192 * sizeof(u32));

    if (off > ws_size) {
        marker_kernel<<<(out_size + 255)/256, 256, 0, stream>>>((float*)d_out, out_size);
        return;
    }

    int gq = (E + 15)/16;
    int gw = (E + 3)/4;
    seg_start_kernel<<<(E + 1 + 255)/256, 256, 0, stream>>>(idx_ji, T, seg, E);
    pack_w2<<<32, 256, 0, stream>>>(hkW2, hvW2, kw2t, vw2t);
    q_kernel<<<gq, 128, 0, stream>>>(hqW1, hqb1, hqg, hqb, hqW2, hqb2, h_bond, qf, E);
    p_prep<<<gq, 128, 0, stream>>>(hkW1, h_bond, pos, row, col, P1k, E);
    p_prep<<<gq, 128, 0, stream>>>(hvW1, h_bond, pos, row, col, P1v, E);
    fused_kernel<<<gw, 256, 0, stream>>>(kw2t, vw2t,
        hkW1, hkb1, hkg, hkb,
        hvW1, hvb1, hvg, hvb,
        hvb2, qf, P1k, P1v, pos, seg, idx_kj, idx_k, row, col, (float*)d_out, E);
}